// Round 2
// baseline (754.193 us; speedup 1.0000x reference)
//
#include <hip/hip_runtime.h>
#include <hip/hip_bf16.h>

#define NN 100000
#define NE 1600000
#define NF 128
#define NH 64
#define NC 16

__device__ __forceinline__ float us2f(unsigned short u) {
    return __uint_as_float(((unsigned int)u) << 16);
}
__device__ __forceinline__ unsigned short f2us_rn(float f) {
    unsigned int u = __float_as_uint(f);
    return (unsigned short)((u + 0x7FFFu + ((u >> 16) & 1u)) >> 16);
}
// scalar load from a buffer that is bf16 (f32=false) or fp32 (f32=true)
__device__ __forceinline__ float ldf(const void* p, size_t i, bool f32) {
    return f32 ? ((const float*)p)[i] : us2f(((const unsigned short*)p)[i]);
}

// ---------------- dtype sniff ----------------
// fp32 N(0,1) data: low-half ushorts are ~uniform random -> ~37% have
// exponent field >= 160 when reinterpreted as bf16. bf16 N(0,1) data: 0%.
__global__ void k_sniff(const unsigned short* __restrict__ xu, int* __restrict__ mode) {
    __shared__ int cnt;
    if (threadIdx.x == 0) cnt = 0;
    __syncthreads();
    int c = 0;
    for (int i = threadIdx.x; i < 4096; i += 256) {
        unsigned int e = (xu[i] >> 7) & 0xFFu;
        if (e >= 160u) c++;
    }
    atomicAdd(&cnt, c);
    __syncthreads();
    if (threadIdx.x == 0) mode[0] = (cnt >= 16) ? 1 : 0;
}

// ---------------- degrees ----------------
__global__ void k_deg(const int* __restrict__ src, const int* __restrict__ dst,
                      int* __restrict__ deg_out, int* __restrict__ deg_in) {
    int i = blockIdx.x * blockDim.x + threadIdx.x;
    if (i < NE) {
        atomicAdd(&deg_out[src[i]], 1);
        atomicAdd(&deg_in[dst[i]], 1);
    }
}

__global__ void k_norm(const int* __restrict__ deg_out, const int* __restrict__ deg_in,
                       float* __restrict__ nsrc, float* __restrict__ ndst) {
    int i = blockIdx.x * blockDim.x + threadIdx.x;
    if (i < NN) {
        nsrc[i] = rsqrtf(fmaxf((float)deg_out[i], 1.0f));
        ndst[i] = rsqrtf(fmaxf((float)deg_in[i], 1.0f));
    }
}

// ---------------- layer 1 GEMM: h1 = (x @ W1) * nsrc ----------------
template<bool H1BF16>
__global__ __launch_bounds__(256) void k_gemm1(
    const void* __restrict__ x, const void* __restrict__ W1,
    const float* __restrict__ nsrc, void* __restrict__ h1,
    const int* __restrict__ mode)
{
    __shared__ float Ws[NF][NH];     // 32 KB
    __shared__ float xs[4][4][NF];   // 8 KB
    const bool f32 = (mode[0] != 0);
    const int tid = threadIdx.x;
    for (int i = tid; i < NF * NH; i += 256) Ws[i / NH][i % NH] = ldf(W1, i, f32);
    __syncthreads();

    const int wave = tid >> 6, lane = tid & 63;
    const int r  = lane >> 4;        // which of the wave's 4 rows this lane stages
    const int k0 = (lane & 15) * 8;  // 8 elements per lane

    for (int g = blockIdx.x; g < NN / 16; g += gridDim.x) {
        const int base = g * 16 + wave * 4;
        __syncthreads();  // previous iteration finished reading xs
        if (f32) {
            const float4* xp = (const float4*)((const float*)x + (size_t)base * NF);
            float4 v0 = xp[lane * 2], v1 = xp[lane * 2 + 1];
            float* dp = &xs[wave][r][k0];
            dp[0]=v0.x; dp[1]=v0.y; dp[2]=v0.z; dp[3]=v0.w;
            dp[4]=v1.x; dp[5]=v1.y; dp[6]=v1.z; dp[7]=v1.w;
        } else {
            const uint4* xp = (const uint4*)((const unsigned short*)x + (size_t)base * NF);
            uint4 v = xp[lane];
            unsigned short us[8];
            *(uint4*)us = v;
            float* dp = &xs[wave][r][k0];
            #pragma unroll
            for (int j = 0; j < 8; ++j) dp[j] = us2f(us[j]);
        }
        __syncthreads();

        float a0 = 0.f, a1 = 0.f, a2 = 0.f, a3 = 0.f;
        #pragma unroll 8
        for (int k = 0; k < NF; ++k) {
            float w = Ws[k][lane];
            a0 = fmaf(xs[wave][0][k], w, a0);
            a1 = fmaf(xs[wave][1][k], w, a1);
            a2 = fmaf(xs[wave][2][k], w, a2);
            a3 = fmaf(xs[wave][3][k], w, a3);
        }
        const float n0 = nsrc[base], n1 = nsrc[base+1], n2 = nsrc[base+2], n3 = nsrc[base+3];
        if (H1BF16) {
            unsigned short* hp = (unsigned short*)h1;
            hp[(size_t)(base+0)*NH+lane] = f2us_rn(a0*n0);
            hp[(size_t)(base+1)*NH+lane] = f2us_rn(a1*n1);
            hp[(size_t)(base+2)*NH+lane] = f2us_rn(a2*n2);
            hp[(size_t)(base+3)*NH+lane] = f2us_rn(a3*n3);
        } else {
            float* hp = (float*)h1;
            hp[(size_t)(base+0)*NH+lane] = a0*n0;
            hp[(size_t)(base+1)*NH+lane] = a1*n1;
            hp[(size_t)(base+2)*NH+lane] = a2*n2;
            hp[(size_t)(base+3)*NH+lane] = a3*n3;
        }
    }
}

// ---------------- layer 1 aggregation: agg1[dst] += h1[src] ----------------
template<bool H1BF16>
__global__ void k_agg1(const int* __restrict__ src, const int* __restrict__ dst,
                       const void* __restrict__ h1, float* __restrict__ agg1) {
    const int lane = threadIdx.x & 63;
    const int wid  = (blockIdx.x * blockDim.x + threadIdx.x) >> 6;
    const int nw   = (gridDim.x * blockDim.x) >> 6;
    for (int e = wid; e < NE; e += nw) {
        const int s = src[e], d = dst[e];
        float v;
        if (H1BF16) v = us2f(((const unsigned short*)h1)[(size_t)s * NH + lane]);
        else        v = ((const float*)h1)[(size_t)s * NH + lane];
        atomicAdd(&agg1[(size_t)d * NH + lane], v);
    }
}

// ---------------- layer 2: h2 = (relu(agg1*ndst + b1) @ W2) * nsrc ----------------
__global__ __launch_bounds__(256) void k_layer2(
    const float* __restrict__ agg1, const float* __restrict__ ndst,
    const float* __restrict__ nsrc, const void* __restrict__ b1,
    const void* __restrict__ W2, float* __restrict__ h2,
    const int* __restrict__ mode)
{
    __shared__ float W2s[NH][NC];   // 4 KB
    __shared__ float ts[4][NH];     // 1 KB
    const bool f32 = (mode[0] != 0);
    const int tid = threadIdx.x;
    for (int i = tid; i < NH * NC; i += 256) W2s[i / NC][i % NC] = ldf(W2, i, f32);
    __syncthreads();

    const int wave = tid >> 6, lane = tid & 63;
    const float bias = ldf(b1, lane, f32);
    for (int g = blockIdx.x; g < NN / 4; g += gridDim.x) {
        const int node = g * 4 + wave;
        __syncthreads();
        float t = fmaxf(fmaf(agg1[(size_t)node * NH + lane], ndst[node], bias), 0.f);
        ts[wave][lane] = t;
        __syncthreads();
        if (lane < NC) {
            float acc = 0.f;
            #pragma unroll
            for (int j = 0; j < NH; ++j) acc = fmaf(ts[wave][j], W2s[j][lane], acc);
            h2[(size_t)node * NC + lane] = acc * nsrc[node];
        }
    }
}

// ---------------- layer 2 aggregation ----------------
__global__ void k_agg2(const int* __restrict__ src, const int* __restrict__ dst,
                       const float* __restrict__ h2, float* __restrict__ agg2) {
    const int t = blockIdx.x * blockDim.x + threadIdx.x;
    const int c = t & 15;
    const int q = t >> 4;
    const int nq = (gridDim.x * blockDim.x) >> 4;
    for (int e = q; e < NE; e += nq) {
        atomicAdd(&agg2[(size_t)dst[e] * NC + c], h2[(size_t)src[e] * NC + c]);
    }
}

// ---------------- epilogue: log_softmax(agg2*ndst + b2) -> out (mode dtype) ----------------
__global__ void k_final(const float* __restrict__ agg2, const float* __restrict__ ndst,
                        const void* __restrict__ b2, void* __restrict__ out,
                        const int* __restrict__ mode) {
    const int t = blockIdx.x * blockDim.x + threadIdx.x;
    const int node = t >> 4, c = t & 15;
    const bool f32 = (mode[0] != 0);
    if (node < NN) {
        float v = fmaf(agg2[(size_t)node * NC + c], ndst[node], ldf(b2, c, f32));
        float m = v;
        #pragma unroll
        for (int off = 8; off >= 1; off >>= 1) m = fmaxf(m, __shfl_xor(m, off, 16));
        float ex = __expf(v - m);
        float s = ex;
        #pragma unroll
        for (int off = 8; off >= 1; off >>= 1) s += __shfl_xor(s, off, 16);
        float r = v - m - __logf(s);
        if (f32) ((float*)out)[(size_t)node * NC + c] = r;
        else ((__hip_bfloat16*)out)[(size_t)node * NC + c] = __float2bfloat16(r);
    }
}

extern "C" void kernel_launch(void* const* d_in, const int* in_sizes, int n_in,
                              void* d_out, int out_size, void* d_ws, size_t ws_size,
                              hipStream_t stream) {
    const void* x  = d_in[0];                 // [NN][NF] bf16 or fp32 (sniffed)
    const int* src = (const int*)d_in[1];
    const int* dst = (const int*)d_in[2];
    const void* W1 = d_in[3];                 // [NF][NH]
    const void* b1 = d_in[4];                 // [NH]
    const void* W2 = d_in[5];                 // [NH][NC]
    const void* b2 = d_in[6];                 // [NC]

    // ---- workspace layout (aliased lifetimes) ----
    // mode: 1 KB | nsrc: NN f32 | ndst: NN f32 | agg1: NN*NH f32 |
    // big:  deg(2*NN int, dead after k_norm) -> h1 (f32 25.6MB or bf16 12.8MB,
    //       dead after k_agg1) -> h2 (NN*NC f32) + agg2 (NN*NC f32)
    char* ws = (char*)d_ws;
    const size_t O_MODE = 0;
    const size_t O_NSRC = 1024;
    const size_t O_NDST = O_NSRC + 400128;           // NN*4 padded
    const size_t O_AGG1 = O_NDST + 400128;
    const size_t O_BIG  = O_AGG1 + (size_t)NN * NH * 4;   // 26,401,280
    const size_t NEED_T1 = O_BIG + (size_t)NN * NH * 4;   // 52,001,280 (h1 fp32)
    const bool tier1 = ws_size >= NEED_T1;                // else h1 bf16 (39.2 MB)

    int*   mode  = (int*)(ws + O_MODE);
    float* nsrc  = (float*)(ws + O_NSRC);
    float* ndst  = (float*)(ws + O_NDST);
    float* agg1  = (float*)(ws + O_AGG1);
    void*  big   = (void*)(ws + O_BIG);
    int*   deg_out = (int*)big;
    int*   deg_in  = deg_out + NN;
    void*  h1    = big;
    float* h2    = (float*)big;
    float* agg2  = h2 + (size_t)NN * NC;

    k_sniff<<<1, 256, 0, stream>>>((const unsigned short*)x, mode);
    hipMemsetAsync(deg_out, 0, 2 * (size_t)NN * sizeof(int), stream);
    k_deg<<<(NE + 255) / 256, 256, 0, stream>>>(src, dst, deg_out, deg_in);
    k_norm<<<(NN + 255) / 256, 256, 0, stream>>>(deg_out, deg_in, nsrc, ndst);
    hipMemsetAsync(agg1, 0, (size_t)NN * NH * sizeof(float), stream);
    if (tier1) {
        k_gemm1<false><<<2048, 256, 0, stream>>>(x, W1, nsrc, h1, mode);
        k_agg1<false><<<8192, 256, 0, stream>>>(src, dst, h1, agg1);
    } else {
        k_gemm1<true><<<2048, 256, 0, stream>>>(x, W1, nsrc, h1, mode);
        k_agg1<true><<<8192, 256, 0, stream>>>(src, dst, h1, agg1);
    }
    // h1 dead from here; big region reused for h2 + agg2
    hipMemsetAsync(agg2, 0, (size_t)NN * NC * sizeof(float), stream);
    k_layer2<<<2048, 256, 0, stream>>>(agg1, ndst, nsrc, b1, W2, h2, mode);
    k_agg2<<<8192, 256, 0, stream>>>(src, dst, h2, agg2);
    k_final<<<(NN * NC + 255) / 256, 256, 0, stream>>>(agg2, ndst, b2, d_out, mode);
}

// Round 3
// 605.534 us; speedup vs baseline: 1.2455x; 1.2455x over previous
//
#include <hip/hip_runtime.h>
#include <hip/hip_bf16.h>

#define NN 100000
#define NE 1600000
#define NF 128
#define NH 64
#define NC 16
#define NB1 391   // ceil(NN/256)

__device__ __forceinline__ float us2f(unsigned short u) {
    return __uint_as_float(((unsigned int)u) << 16);
}
__device__ __forceinline__ unsigned short f2us_rn(float f) {
    unsigned int u = __float_as_uint(f);
    return (unsigned short)((u + 0x7FFFu + ((u >> 16) & 1u)) >> 16);
}
__device__ __forceinline__ float ldf(const void* p, size_t i, bool f32) {
    return f32 ? ((const float*)p)[i] : us2f(((const unsigned short*)p)[i]);
}

// ---------------- dtype sniff (validated R2) ----------------
__global__ void k_sniff(const unsigned short* __restrict__ xu, int* __restrict__ mode) {
    __shared__ int cnt;
    if (threadIdx.x == 0) cnt = 0;
    __syncthreads();
    int c = 0;
    for (int i = threadIdx.x; i < 4096; i += 256) {
        unsigned int e = (xu[i] >> 7) & 0xFFu;
        if (e >= 160u) c++;
    }
    atomicAdd(&cnt, c);
    __syncthreads();
    if (threadIdx.x == 0) mode[0] = (cnt >= 16) ? 1 : 0;
}

// ---------------- degrees ----------------
__global__ void k_deg(const int* __restrict__ src, const int* __restrict__ dst,
                      int* __restrict__ deg_out, int* __restrict__ deg_in) {
    int i = blockIdx.x * blockDim.x + threadIdx.x;
    if (i < NE) {
        atomicAdd(&deg_out[src[i]], 1);
        atomicAdd(&deg_in[dst[i]], 1);
    }
}

// ---------------- CSR build: scan of in-degrees ----------------
__global__ void k_scan_a(const int* __restrict__ deg_in, int* __restrict__ bsum) {
    __shared__ int s[256];
    int i = blockIdx.x * 256 + threadIdx.x;
    s[threadIdx.x] = (i < NN) ? deg_in[i] : 0;
    __syncthreads();
    for (int off = 128; off > 0; off >>= 1) {
        if (threadIdx.x < off) s[threadIdx.x] += s[threadIdx.x + off];
        __syncthreads();
    }
    if (threadIdx.x == 0) bsum[blockIdx.x] = s[0];
}

__global__ void k_scan_b(const int* __restrict__ bsum, int* __restrict__ boff) {
    __shared__ int s[512];
    int t = threadIdx.x;
    s[t] = (t < NB1) ? bsum[t] : 0;
    __syncthreads();
    for (int off = 1; off < 512; off <<= 1) {
        int v = (t >= off) ? s[t - off] : 0;
        __syncthreads();
        s[t] += v;
        __syncthreads();
    }
    if (t < NB1) boff[t] = (t == 0) ? 0 : s[t - 1];
}

// per-block scan -> row_off/cursor; also fused degree-norm computation
__global__ void k_scan_c(const int* __restrict__ deg_in, const int* __restrict__ deg_out,
                         const int* __restrict__ boff, int* __restrict__ row_off,
                         int* __restrict__ cursor, float* __restrict__ nsrc,
                         float* __restrict__ ndst) {
    __shared__ int s[256];
    int t = threadIdx.x;
    int i = blockIdx.x * 256 + t;
    int d = (i < NN) ? deg_in[i] : 0;
    s[t] = d;
    __syncthreads();
    for (int off = 1; off < 256; off <<= 1) {
        int v = (t >= off) ? s[t - off] : 0;
        __syncthreads();
        s[t] += v;
        __syncthreads();
    }
    int excl = s[t] - d + boff[blockIdx.x];
    if (i < NN) {
        row_off[i] = excl;
        cursor[i]  = excl;
        ndst[i] = rsqrtf(fmaxf((float)d, 1.0f));
        nsrc[i] = rsqrtf(fmaxf((float)deg_out[i], 1.0f));
        if (i == NN - 1) row_off[NN] = excl + d;
    }
}

__global__ void k_scatter(const int* __restrict__ src, const int* __restrict__ dst,
                          int* __restrict__ cursor, int* __restrict__ srcs_sorted) {
    int e = blockIdx.x * blockDim.x + threadIdx.x;
    if (e < NE) {
        int p = atomicAdd(&cursor[dst[e]], 1);
        srcs_sorted[p] = src[e];
    }
}

// ---------------- layer 1 GEMM: h1 = (x @ W1) * nsrc ----------------
template<bool H1BF16>
__global__ __launch_bounds__(256) void k_gemm1(
    const void* __restrict__ x, const void* __restrict__ W1,
    const float* __restrict__ nsrc, void* __restrict__ h1,
    const int* __restrict__ mode)
{
    __shared__ float Ws[NF][NH];     // 32 KB
    __shared__ float xs[4][4][NF];   // 8 KB
    const bool f32 = (mode[0] != 0);
    const int tid = threadIdx.x;
    for (int i = tid; i < NF * NH; i += 256) Ws[i / NH][i % NH] = ldf(W1, i, f32);
    __syncthreads();

    const int wave = tid >> 6, lane = tid & 63;
    const int r  = lane >> 4;
    const int k0 = (lane & 15) * 8;

    for (int g = blockIdx.x; g < NN / 16; g += gridDim.x) {
        const int base = g * 16 + wave * 4;
        __syncthreads();
        if (f32) {
            const float4* xp = (const float4*)((const float*)x + (size_t)base * NF);
            float4 v0 = xp[lane * 2], v1 = xp[lane * 2 + 1];
            float* dp = &xs[wave][r][k0];
            dp[0]=v0.x; dp[1]=v0.y; dp[2]=v0.z; dp[3]=v0.w;
            dp[4]=v1.x; dp[5]=v1.y; dp[6]=v1.z; dp[7]=v1.w;
        } else {
            const uint4* xp = (const uint4*)((const unsigned short*)x + (size_t)base * NF);
            uint4 v = xp[lane];
            unsigned short us[8];
            *(uint4*)us = v;
            float* dp = &xs[wave][r][k0];
            #pragma unroll
            for (int j = 0; j < 8; ++j) dp[j] = us2f(us[j]);
        }
        __syncthreads();

        float a0 = 0.f, a1 = 0.f, a2 = 0.f, a3 = 0.f;
        #pragma unroll 8
        for (int k = 0; k < NF; ++k) {
            float w = Ws[k][lane];
            a0 = fmaf(xs[wave][0][k], w, a0);
            a1 = fmaf(xs[wave][1][k], w, a1);
            a2 = fmaf(xs[wave][2][k], w, a2);
            a3 = fmaf(xs[wave][3][k], w, a3);
        }
        const float n0 = nsrc[base], n1 = nsrc[base+1], n2 = nsrc[base+2], n3 = nsrc[base+3];
        if (H1BF16) {
            unsigned short* hp = (unsigned short*)h1;
            hp[(size_t)(base+0)*NH+lane] = f2us_rn(a0*n0);
            hp[(size_t)(base+1)*NH+lane] = f2us_rn(a1*n1);
            hp[(size_t)(base+2)*NH+lane] = f2us_rn(a2*n2);
            hp[(size_t)(base+3)*NH+lane] = f2us_rn(a3*n3);
        } else {
            float* hp = (float*)h1;
            hp[(size_t)(base+0)*NH+lane] = a0*n0;
            hp[(size_t)(base+1)*NH+lane] = a1*n1;
            hp[(size_t)(base+2)*NH+lane] = a2*n2;
            hp[(size_t)(base+3)*NH+lane] = a3*n3;
        }
    }
}

// ---------------- fused layer-1 aggregation + relu + W2 GEMM ----------------
// wave per dst row; 4 edge slots x 16 feature-quads; reduce-scatter for W2.
template<bool H1BF16>
__global__ __launch_bounds__(256) void k_agg1csr(
    const int* __restrict__ row_off, const int* __restrict__ srcs,
    const void* __restrict__ h1, const float* __restrict__ ndst,
    const float* __restrict__ nsrc, const void* __restrict__ b1,
    const void* __restrict__ W2, const int* __restrict__ mode,
    float* __restrict__ h2)
{
    const bool f32 = (mode[0] != 0);
    const int lane = threadIdx.x & 63;
    const int q  = lane >> 4;    // edge slot 0..3
    const int li = lane & 15;    // feature quad: feats 4li..4li+3

    // loop-invariant per-lane constants
    float bias0 = ldf(b1, 4*li+0, f32), bias1 = ldf(b1, 4*li+1, f32);
    float bias2 = ldf(b1, 4*li+2, f32), bias3 = ldf(b1, 4*li+3, f32);
    float w2r0[16], w2r1[16], w2r2[16], w2r3[16];
    #pragma unroll
    for (int c = 0; c < 16; ++c) {
        w2r0[c] = ldf(W2, (size_t)(4*li+0)*NC + c, f32);
        w2r1[c] = ldf(W2, (size_t)(4*li+1)*NC + c, f32);
        w2r2[c] = ldf(W2, (size_t)(4*li+2)*NC + c, f32);
        w2r3[c] = ldf(W2, (size_t)(4*li+3)*NC + c, f32);
    }

    const int wid = (blockIdx.x * blockDim.x + threadIdx.x) >> 6;
    const int nw  = (gridDim.x * blockDim.x) >> 6;

    for (int rrow = wid; rrow < NN; rrow += nw) {
        const int beg = row_off[rrow], end = row_off[rrow + 1];
        float ax = 0.f, ay = 0.f, az = 0.f, aw = 0.f;
        int i = beg + q;
        int s = (i < end) ? srcs[i] : 0;
        while (i < end) {
            const int inext = i + 4;
            const int snext = (inext < end) ? srcs[inext] : 0;
            if (H1BF16) {
                uint2 v = *(const uint2*)((const unsigned short*)h1 + (size_t)s * NH + 4*li);
                ax += us2f((unsigned short)(v.x & 0xFFFF));
                ay += us2f((unsigned short)(v.x >> 16));
                az += us2f((unsigned short)(v.y & 0xFFFF));
                aw += us2f((unsigned short)(v.y >> 16));
            } else {
                float4 v = *(const float4*)((const float*)h1 + (size_t)s * NH + 4*li);
                ax += v.x; ay += v.y; az += v.z; aw += v.w;
            }
            i = inext; s = snext;
        }
        // merge 4 edge slots (xor16, xor32)
        ax += __shfl_xor(ax, 16); ay += __shfl_xor(ay, 16);
        az += __shfl_xor(az, 16); aw += __shfl_xor(aw, 16);
        ax += __shfl_xor(ax, 32); ay += __shfl_xor(ay, 32);
        az += __shfl_xor(az, 32); aw += __shfl_xor(aw, 32);

        const float nd = ndst[rrow];
        const float t0 = fmaxf(fmaf(ax, nd, bias0), 0.f);
        const float t1 = fmaxf(fmaf(ay, nd, bias1), 0.f);
        const float t2 = fmaxf(fmaf(az, nd, bias2), 0.f);
        const float t3 = fmaxf(fmaf(aw, nd, bias3), 0.f);

        float qv[16];
        #pragma unroll
        for (int c = 0; c < 16; ++c)
            qv[c] = fmaf(t0, w2r0[c], fmaf(t1, w2r1[c], fmaf(t2, w2r2[c], t3 * w2r3[c])));

        // reduce-scatter across the 16 li-lanes: lane li ends with c = li
        {
            const bool hi = (li & 8);
            #pragma unroll
            for (int j = 0; j < 8; ++j) {
                float keep = hi ? qv[j+8] : qv[j];
                float give = hi ? qv[j] : qv[j+8];
                qv[j] = keep + __shfl_xor(give, 8);
            }
        }
        {
            const bool hi = (li & 4);
            #pragma unroll
            for (int j = 0; j < 4; ++j) {
                float keep = hi ? qv[j+4] : qv[j];
                float give = hi ? qv[j] : qv[j+4];
                qv[j] = keep + __shfl_xor(give, 4);
            }
        }
        {
            const bool hi = (li & 2);
            #pragma unroll
            for (int j = 0; j < 2; ++j) {
                float keep = hi ? qv[j+2] : qv[j];
                float give = hi ? qv[j] : qv[j+2];
                qv[j] = keep + __shfl_xor(give, 2);
            }
        }
        {
            const bool hi = (li & 1);
            float keep = hi ? qv[1] : qv[0];
            float give = hi ? qv[0] : qv[1];
            qv[0] = keep + __shfl_xor(give, 1);
        }
        if (lane < 16) h2[(size_t)rrow * NC + li] = qv[0] * nsrc[rrow];
    }
}

// ---------------- fused layer-2 aggregation + bias + log_softmax ----------------
__global__ __launch_bounds__(256) void k_out(
    const int* __restrict__ row_off, const int* __restrict__ srcs,
    const float* __restrict__ h2, const float* __restrict__ ndst,
    const void* __restrict__ b2, const int* __restrict__ mode,
    void* __restrict__ out)
{
    const bool f32 = (mode[0] != 0);
    const int lane = threadIdx.x & 63;
    const int q  = lane >> 4;
    const int li = lane & 15;
    const float b2v = ldf(b2, li, f32);

    const int wid = (blockIdx.x * blockDim.x + threadIdx.x) >> 6;
    const int nw  = (gridDim.x * blockDim.x) >> 6;

    for (int r = wid; r < NN; r += nw) {
        const int beg = row_off[r], end = row_off[r + 1];
        float a = 0.f;
        int i = beg + q;
        int s = (i < end) ? srcs[i] : 0;
        while (i < end) {
            const int inext = i + 4;
            const int snext = (inext < end) ? srcs[inext] : 0;
            a += h2[(size_t)s * NC + li];
            i = inext; s = snext;
        }
        a += __shfl_xor(a, 16);
        a += __shfl_xor(a, 32);
        float v = fmaf(a, ndst[r], b2v);
        float m = v;
        #pragma unroll
        for (int off = 8; off >= 1; off >>= 1) m = fmaxf(m, __shfl_xor(m, off));
        float ex = __expf(v - m);
        float sm = ex;
        #pragma unroll
        for (int off = 8; off >= 1; off >>= 1) sm += __shfl_xor(sm, off);
        float res = v - m - __logf(sm);
        if (lane < 16) {
            if (f32) ((float*)out)[(size_t)r * NC + li] = res;
            else ((__hip_bfloat16*)out)[(size_t)r * NC + li] = __float2bfloat16(res);
        }
    }
}

extern "C" void kernel_launch(void* const* d_in, const int* in_sizes, int n_in,
                              void* d_out, int out_size, void* d_ws, size_t ws_size,
                              hipStream_t stream) {
    const void* x  = d_in[0];
    const int* src = (const int*)d_in[1];
    const int* dst = (const int*)d_in[2];
    const void* W1 = d_in[3];
    const void* b1 = d_in[4];
    const void* W2 = d_in[5];
    const void* b2 = d_in[6];

    // ---- workspace layout ----
    char* ws = (char*)d_ws;
    const size_t O_MODE = 0;                               // 1 KB
    const size_t O_DEG  = 1024;                            // deg_out NN + deg_in NN (800000 B)
    const size_t O_NSRC = O_DEG  + 800000;                 // 400000
    const size_t O_NDST = O_NSRC + 400000;                 // 400000
    const size_t O_ROW  = O_NDST + 400000;                 // (NN+1)*4 -> pad 400128
    const size_t O_CUR  = O_ROW  + 400128;                 // 400000 -> pad 400128
    const size_t O_BS   = O_CUR  + 400128;                 // bsum 2048 + boff 2048
    const size_t O_SRCS = O_BS   + 4096;                   // NE*4 = 6400000
    const size_t O_H2   = O_SRCS + 6400000;                // NN*16*4 = 6400000
    const size_t O_H1   = O_H2   + 6400000;                // fp32 25.6 MB / bf16 12.8 MB
    const size_t NEED_T1 = O_H1 + (size_t)NN * NH * 4;     // ~40.8 MB
    const bool tier1 = ws_size >= NEED_T1;                 // else bf16 h1 (~28 MB)

    int*   mode    = (int*)(ws + O_MODE);
    int*   deg_out = (int*)(ws + O_DEG);
    int*   deg_in  = deg_out + NN;
    float* nsrc    = (float*)(ws + O_NSRC);
    float* ndst    = (float*)(ws + O_NDST);
    int*   row_off = (int*)(ws + O_ROW);
    int*   cursor  = (int*)(ws + O_CUR);
    int*   bsum    = (int*)(ws + O_BS);
    int*   boff    = (int*)(ws + O_BS + 2048);
    int*   srcs_s  = (int*)(ws + O_SRCS);
    float* h2      = (float*)(ws + O_H2);
    void*  h1      = (void*)(ws + O_H1);

    k_sniff<<<1, 256, 0, stream>>>((const unsigned short*)x, mode);
    hipMemsetAsync(deg_out, 0, 2 * (size_t)NN * sizeof(int), stream);
    k_deg<<<(NE + 255) / 256, 256, 0, stream>>>(src, dst, deg_out, deg_in);
    k_scan_a<<<NB1, 256, 0, stream>>>(deg_in, bsum);
    k_scan_b<<<1, 512, 0, stream>>>(bsum, boff);
    k_scan_c<<<NB1, 256, 0, stream>>>(deg_in, deg_out, boff, row_off, cursor, nsrc, ndst);
    k_scatter<<<(NE + 255) / 256, 256, 0, stream>>>(src, dst, cursor, srcs_s);
    if (tier1) {
        k_gemm1<false><<<2048, 256, 0, stream>>>(x, W1, nsrc, h1, mode);
        k_agg1csr<false><<<2048, 256, 0, stream>>>(row_off, srcs_s, h1, ndst, nsrc, b1, W2, mode, h2);
    } else {
        k_gemm1<true><<<2048, 256, 0, stream>>>(x, W1, nsrc, h1, mode);
        k_agg1csr<true><<<2048, 256, 0, stream>>>(row_off, srcs_s, h1, ndst, nsrc, b1, W2, mode, h2);
    }
    k_out<<<2048, 256, 0, stream>>>(row_off, srcs_s, h2, ndst, b2, mode, d_out);
}

// Round 4
// 492.760 us; speedup vs baseline: 1.5305x; 1.2289x over previous
//
#include <hip/hip_runtime.h>
#include <hip/hip_bf16.h>

#define NN 100000
#define NE 1600000
#define NF 128
#define NH 64
#define NC 16
#define NB1 391   // ceil(NN/256)

__device__ __forceinline__ float us2f(unsigned short u) {
    return __uint_as_float(((unsigned int)u) << 16);
}
__device__ __forceinline__ unsigned short f2us_rn(float f) {
    unsigned int u = __float_as_uint(f);
    return (unsigned short)((u + 0x7FFFu + ((u >> 16) & 1u)) >> 16);
}
__device__ __forceinline__ float ldf(const void* p, size_t i, bool f32) {
    return f32 ? ((const float*)p)[i] : us2f(((const unsigned short*)p)[i]);
}

// ---------------- dtype sniff (validated R2) ----------------
__global__ void k_sniff(const unsigned short* __restrict__ xu, int* __restrict__ mode) {
    __shared__ int cnt;
    if (threadIdx.x == 0) cnt = 0;
    __syncthreads();
    int c = 0;
    for (int i = threadIdx.x; i < 4096; i += 256) {
        unsigned int e = (xu[i] >> 7) & 0xFFu;
        if (e >= 160u) c++;
    }
    atomicAdd(&cnt, c);
    __syncthreads();
    if (threadIdx.x == 0) mode[0] = (cnt >= 16) ? 1 : 0;
}

// ---------------- degrees ----------------
__global__ void k_deg(const int* __restrict__ src, const int* __restrict__ dst,
                      int* __restrict__ deg_out, int* __restrict__ deg_in) {
    int i = blockIdx.x * blockDim.x + threadIdx.x;
    if (i < NE) {
        atomicAdd(&deg_out[src[i]], 1);
        atomicAdd(&deg_in[dst[i]], 1);
    }
}

// ---------------- CSR build: scan of in-degrees ----------------
__global__ void k_scan_a(const int* __restrict__ deg_in, int* __restrict__ bsum) {
    __shared__ int s[256];
    int i = blockIdx.x * 256 + threadIdx.x;
    s[threadIdx.x] = (i < NN) ? deg_in[i] : 0;
    __syncthreads();
    for (int off = 128; off > 0; off >>= 1) {
        if (threadIdx.x < off) s[threadIdx.x] += s[threadIdx.x + off];
        __syncthreads();
    }
    if (threadIdx.x == 0) bsum[blockIdx.x] = s[0];
}

__global__ void k_scan_b(const int* __restrict__ bsum, int* __restrict__ boff) {
    __shared__ int s[512];
    int t = threadIdx.x;
    s[t] = (t < NB1) ? bsum[t] : 0;
    __syncthreads();
    for (int off = 1; off < 512; off <<= 1) {
        int v = (t >= off) ? s[t - off] : 0;
        __syncthreads();
        s[t] += v;
        __syncthreads();
    }
    if (t < NB1) boff[t] = (t == 0) ? 0 : s[t - 1];
}

__global__ void k_scan_c(const int* __restrict__ deg_in, const int* __restrict__ deg_out,
                         const int* __restrict__ boff, int* __restrict__ row_off,
                         int* __restrict__ cursor, float* __restrict__ nsrc,
                         float* __restrict__ ndst) {
    __shared__ int s[256];
    int t = threadIdx.x;
    int i = blockIdx.x * 256 + t;
    int d = (i < NN) ? deg_in[i] : 0;
    s[t] = d;
    __syncthreads();
    for (int off = 1; off < 256; off <<= 1) {
        int v = (t >= off) ? s[t - off] : 0;
        __syncthreads();
        s[t] += v;
        __syncthreads();
    }
    int excl = s[t] - d + boff[blockIdx.x];
    if (i < NN) {
        row_off[i] = excl;
        cursor[i]  = excl;
        ndst[i] = rsqrtf(fmaxf((float)d, 1.0f));
        nsrc[i] = rsqrtf(fmaxf((float)deg_out[i], 1.0f));
        if (i == NN - 1) row_off[NN] = excl + d;
    }
}

__global__ void k_scatter(const int* __restrict__ src, const int* __restrict__ dst,
                          int* __restrict__ cursor, int* __restrict__ srcs_sorted) {
    int e = blockIdx.x * blockDim.x + threadIdx.x;
    if (e < NE) {
        int p = atomicAdd(&cursor[dst[e]], 1);
        srcs_sorted[p] = src[e];
    }
}

// ---------------- layer 1 GEMM: h1 = bf16((x @ W1) * nsrc) ----------------
__global__ __launch_bounds__(256) void k_gemm1(
    const void* __restrict__ x, const void* __restrict__ W1,
    const float* __restrict__ nsrc, unsigned short* __restrict__ h1,
    const int* __restrict__ mode)
{
    __shared__ float Ws[NF][NH];     // 32 KB
    __shared__ float xs[4][4][NF];   // 8 KB
    const bool f32 = (mode[0] != 0);
    const int tid = threadIdx.x;
    for (int i = tid; i < NF * NH; i += 256) Ws[i / NH][i % NH] = ldf(W1, i, f32);
    __syncthreads();

    const int wave = tid >> 6, lane = tid & 63;
    const int r  = lane >> 4;
    const int k0 = (lane & 15) * 8;

    for (int g = blockIdx.x; g < NN / 16; g += gridDim.x) {
        const int base = g * 16 + wave * 4;
        __syncthreads();
        if (f32) {
            const float4* xp = (const float4*)((const float*)x + (size_t)base * NF);
            float4 v0 = xp[lane * 2], v1 = xp[lane * 2 + 1];
            float* dp = &xs[wave][r][k0];
            dp[0]=v0.x; dp[1]=v0.y; dp[2]=v0.z; dp[3]=v0.w;
            dp[4]=v1.x; dp[5]=v1.y; dp[6]=v1.z; dp[7]=v1.w;
        } else {
            const uint4* xp = (const uint4*)((const unsigned short*)x + (size_t)base * NF);
            uint4 v = xp[lane];
            unsigned short us[8];
            *(uint4*)us = v;
            float* dp = &xs[wave][r][k0];
            #pragma unroll
            for (int j = 0; j < 8; ++j) dp[j] = us2f(us[j]);
        }
        __syncthreads();

        float a0 = 0.f, a1 = 0.f, a2 = 0.f, a3 = 0.f;
        #pragma unroll 4
        for (int k = 0; k < NF; k += 4) {
            float4 x0 = *(const float4*)&xs[wave][0][k];
            float4 x1 = *(const float4*)&xs[wave][1][k];
            float4 x2 = *(const float4*)&xs[wave][2][k];
            float4 x3 = *(const float4*)&xs[wave][3][k];
            float w0 = Ws[k][lane], w1 = Ws[k+1][lane];
            float w2 = Ws[k+2][lane], w3 = Ws[k+3][lane];
            a0 = fmaf(x0.x,w0,fmaf(x0.y,w1,fmaf(x0.z,w2,fmaf(x0.w,w3,a0))));
            a1 = fmaf(x1.x,w0,fmaf(x1.y,w1,fmaf(x1.z,w2,fmaf(x1.w,w3,a1))));
            a2 = fmaf(x2.x,w0,fmaf(x2.y,w1,fmaf(x2.z,w2,fmaf(x2.w,w3,a2))));
            a3 = fmaf(x3.x,w0,fmaf(x3.y,w1,fmaf(x3.z,w2,fmaf(x3.w,w3,a3))));
        }
        h1[(size_t)(base+0)*NH+lane] = f2us_rn(a0 * nsrc[base+0]);
        h1[(size_t)(base+1)*NH+lane] = f2us_rn(a1 * nsrc[base+1]);
        h1[(size_t)(base+2)*NH+lane] = f2us_rn(a2 * nsrc[base+2]);
        h1[(size_t)(base+3)*NH+lane] = f2us_rn(a3 * nsrc[base+3]);
    }
}

// ---------------- fused layer-1 aggregation + relu + W2 GEMM ----------------
// wave per dst row; 4 edge slots (q) x 16 feature-quads (li); bf16 h1 gathers,
// 2x unrolled (dual accumulators). W2 stage: lane (q,li) computes partial for
// columns {q+4m} from its 4 feats (16 regs), then xor-butterfly over li.
__global__ __launch_bounds__(256) void k_agg1csr(
    const int* __restrict__ row_off, const int* __restrict__ srcs,
    const unsigned short* __restrict__ h1, const float* __restrict__ ndst,
    const float* __restrict__ nsrc, const void* __restrict__ b1,
    const void* __restrict__ W2, const int* __restrict__ mode,
    unsigned short* __restrict__ h2)
{
    const bool f32 = (mode[0] != 0);
    const int lane = threadIdx.x & 63;
    const int q  = lane >> 4;    // edge slot / column subset
    const int li = lane & 15;    // feature quad: feats 4li..4li+3

    const float bias0 = ldf(b1, 4*li+0, f32), bias1 = ldf(b1, 4*li+1, f32);
    const float bias2 = ldf(b1, 4*li+2, f32), bias3 = ldf(b1, 4*li+3, f32);
    // W2 rows 4li+j, cols q+4m
    float w2[4][4];
    #pragma unroll
    for (int j = 0; j < 4; ++j)
        #pragma unroll
        for (int m = 0; m < 4; ++m)
            w2[j][m] = ldf(W2, (size_t)(4*li+j)*NC + (q + 4*m), f32);

    const int wid = (blockIdx.x * blockDim.x + threadIdx.x) >> 6;
    const int nw  = (gridDim.x * blockDim.x) >> 6;

    for (int row = wid; row < NN; row += nw) {
        const int beg = row_off[row], end = row_off[row + 1];
        float ax = 0.f, ay = 0.f, az = 0.f, aw = 0.f;
        float bx = 0.f, by = 0.f, bz = 0.f, bw = 0.f;
        int i = beg + q;
        int s0 = (i     < end) ? srcs[i]     : 0;
        int s1 = (i + 4 < end) ? srcs[i + 4] : 0;
        while (i + 4 < end) {
            uint2 v0 = *(const uint2*)(h1 + (size_t)s0 * NH + 4*li);
            uint2 v1 = *(const uint2*)(h1 + (size_t)s1 * NH + 4*li);
            const int inext = i + 8;
            s0 = (inext     < end) ? srcs[inext]     : 0;
            s1 = (inext + 4 < end) ? srcs[inext + 4] : 0;
            ax += us2f((unsigned short)(v0.x & 0xFFFF));
            ay += us2f((unsigned short)(v0.x >> 16));
            az += us2f((unsigned short)(v0.y & 0xFFFF));
            aw += us2f((unsigned short)(v0.y >> 16));
            bx += us2f((unsigned short)(v1.x & 0xFFFF));
            by += us2f((unsigned short)(v1.x >> 16));
            bz += us2f((unsigned short)(v1.y & 0xFFFF));
            bw += us2f((unsigned short)(v1.y >> 16));
            i = inext;
        }
        if (i < end) {
            uint2 v0 = *(const uint2*)(h1 + (size_t)s0 * NH + 4*li);
            ax += us2f((unsigned short)(v0.x & 0xFFFF));
            ay += us2f((unsigned short)(v0.x >> 16));
            az += us2f((unsigned short)(v0.y & 0xFFFF));
            aw += us2f((unsigned short)(v0.y >> 16));
        }
        ax += bx; ay += by; az += bz; aw += bw;
        // merge 4 edge slots -> all 64 lanes hold full sums for their li
        ax += __shfl_xor(ax, 16); ay += __shfl_xor(ay, 16);
        az += __shfl_xor(az, 16); aw += __shfl_xor(aw, 16);
        ax += __shfl_xor(ax, 32); ay += __shfl_xor(ay, 32);
        az += __shfl_xor(az, 32); aw += __shfl_xor(aw, 32);

        const float nd = ndst[row];
        const float t0 = fmaxf(fmaf(ax, nd, bias0), 0.f);
        const float t1 = fmaxf(fmaf(ay, nd, bias1), 0.f);
        const float t2 = fmaxf(fmaf(az, nd, bias2), 0.f);
        const float t3 = fmaxf(fmaf(aw, nd, bias3), 0.f);

        float p0 = fmaf(t0,w2[0][0],fmaf(t1,w2[1][0],fmaf(t2,w2[2][0],t3*w2[3][0])));
        float p1 = fmaf(t0,w2[0][1],fmaf(t1,w2[1][1],fmaf(t2,w2[2][1],t3*w2[3][1])));
        float p2 = fmaf(t0,w2[0][2],fmaf(t1,w2[1][2],fmaf(t2,w2[2][2],t3*w2[3][2])));
        float p3 = fmaf(t0,w2[0][3],fmaf(t1,w2[1][3],fmaf(t2,w2[2][3],t3*w2[3][3])));
        // reduce over the 16 li lanes (bits 0..3)
        #pragma unroll
        for (int off = 1; off <= 8; off <<= 1) {
            p0 += __shfl_xor(p0, off);
            p1 += __shfl_xor(p1, off);
            p2 += __shfl_xor(p2, off);
            p3 += __shfl_xor(p3, off);
        }
        if (li < 4) {
            float v = (li == 0) ? p0 : (li == 1) ? p1 : (li == 2) ? p2 : p3;
            h2[(size_t)row * NC + q + 4*li] = f2us_rn(v * nsrc[row]);
        }
    }
}

// ---------------- fused layer-2 aggregation + bias + log_softmax ----------------
__global__ __launch_bounds__(256) void k_out(
    const int* __restrict__ row_off, const int* __restrict__ srcs,
    const unsigned short* __restrict__ h2, const float* __restrict__ ndst,
    const void* __restrict__ b2, const int* __restrict__ mode,
    void* __restrict__ out)
{
    const bool f32 = (mode[0] != 0);
    const int lane = threadIdx.x & 63;
    const int q  = lane >> 4;
    const int li = lane & 15;
    const float b2v = ldf(b2, li, f32);

    const int wid = (blockIdx.x * blockDim.x + threadIdx.x) >> 6;
    const int nw  = (gridDim.x * blockDim.x) >> 6;

    for (int r = wid; r < NN; r += nw) {
        const int beg = row_off[r], end = row_off[r + 1];
        float a = 0.f, b = 0.f;
        int i = beg + q;
        int s0 = (i     < end) ? srcs[i]     : 0;
        int s1 = (i + 4 < end) ? srcs[i + 4] : 0;
        while (i + 4 < end) {
            float va = us2f(h2[(size_t)s0 * NC + li]);
            float vb = us2f(h2[(size_t)s1 * NC + li]);
            const int inext = i + 8;
            s0 = (inext     < end) ? srcs[inext]     : 0;
            s1 = (inext + 4 < end) ? srcs[inext + 4] : 0;
            a += va; b += vb;
            i = inext;
        }
        if (i < end) a += us2f(h2[(size_t)s0 * NC + li]);
        a += b;
        a += __shfl_xor(a, 16);
        a += __shfl_xor(a, 32);
        float v = fmaf(a, ndst[r], b2v);
        float m = v;
        #pragma unroll
        for (int off = 8; off >= 1; off >>= 1) m = fmaxf(m, __shfl_xor(m, off));
        float ex = __expf(v - m);
        float sm = ex;
        #pragma unroll
        for (int off = 8; off >= 1; off >>= 1) sm += __shfl_xor(sm, off);
        float res = v - m - __logf(sm);
        if (lane < 16) {
            if (f32) ((float*)out)[(size_t)r * NC + li] = res;
            else ((__hip_bfloat16*)out)[(size_t)r * NC + li] = __float2bfloat16(res);
        }
    }
}

extern "C" void kernel_launch(void* const* d_in, const int* in_sizes, int n_in,
                              void* d_out, int out_size, void* d_ws, size_t ws_size,
                              hipStream_t stream) {
    const void* x  = d_in[0];
    const int* src = (const int*)d_in[1];
    const int* dst = (const int*)d_in[2];
    const void* W1 = d_in[3];
    const void* b1 = d_in[4];
    const void* W2 = d_in[5];
    const void* b2 = d_in[6];

    // ---- workspace layout (all offsets 128B-aligned) ----
    char* ws = (char*)d_ws;
    const size_t O_MODE = 0;                     // 1 KB
    const size_t O_DEG  = 1024;                  // 800000 (deg_out NN + deg_in NN)
    const size_t O_NSRC = O_DEG  + 800000;
    const size_t O_NDST = O_NSRC + 400000;
    const size_t O_ROW  = O_NDST + 400000;       // (NN+1)*4 padded
    const size_t O_CUR  = O_ROW  + 400128;
    const size_t O_BS   = O_CUR  + 400128;       // bsum 2048 + boff 2048
    const size_t O_SRCS = O_BS   + 4096;         // NE*4 = 6400000
    const size_t O_H2   = O_SRCS + 6400000;      // NN*NC*2 = 3200000 (bf16)
    const size_t O_H1   = O_H2   + 3200000;      // NN*NH*2 = 12800000 (bf16)
    // total ~24.8 MB

    int*   mode    = (int*)(ws + O_MODE);
    int*   deg_out = (int*)(ws + O_DEG);
    int*   deg_in  = deg_out + NN;
    float* nsrc    = (float*)(ws + O_NSRC);
    float* ndst    = (float*)(ws + O_NDST);
    int*   row_off = (int*)(ws + O_ROW);
    int*   cursor  = (int*)(ws + O_CUR);
    int*   bsum    = (int*)(ws + O_BS);
    int*   boff    = (int*)(ws + O_BS + 2048);
    int*   srcs_s  = (int*)(ws + O_SRCS);
    unsigned short* h2 = (unsigned short*)(ws + O_H2);
    unsigned short* h1 = (unsigned short*)(ws + O_H1);

    k_sniff<<<1, 256, 0, stream>>>((const unsigned short*)x, mode);
    hipMemsetAsync(deg_out, 0, 2 * (size_t)NN * sizeof(int), stream);
    k_deg<<<(NE + 255) / 256, 256, 0, stream>>>(src, dst, deg_out, deg_in);
    k_scan_a<<<NB1, 256, 0, stream>>>(deg_in, bsum);
    k_scan_b<<<1, 512, 0, stream>>>(bsum, boff);
    k_scan_c<<<NB1, 256, 0, stream>>>(deg_in, deg_out, boff, row_off, cursor, nsrc, ndst);
    k_scatter<<<(NE + 255) / 256, 256, 0, stream>>>(src, dst, cursor, srcs_s);
    k_gemm1<<<2048, 256, 0, stream>>>(x, W1, nsrc, h1, mode);
    k_agg1csr<<<2048, 256, 0, stream>>>(row_off, srcs_s, h1, ndst, nsrc, b1, W2, mode, h2);
    k_out<<<2048, 256, 0, stream>>>(row_off, srcs_s, h2, ndst, b2, mode, d_out);
}